// Round 14
// baseline (61.143 us; speedup 1.0000x reference)
//
#include <hip/hip_runtime.h>
#include <stdint.h>

#define SEQ 4096
#define DH  64
#define NB  64
#define NH  12

typedef float  f32x4   __attribute__((ext_vector_type(4)));
typedef float  f32x16  __attribute__((ext_vector_type(16)));
typedef short  s16x8   __attribute__((ext_vector_type(8)));
typedef unsigned short ushort_t;
typedef unsigned long long u64;

__device__ __forceinline__ unsigned short f2bf(float x){
    union { float f; unsigned u; } c; c.f = x;
    unsigned u = c.u;
    u += 0x7fffu + ((u >> 16) & 1u);   // round-to-nearest-even
    return (unsigned short)(u >> 16);
}

__device__ __forceinline__ unsigned cvtpk(float lo, float hi){
    unsigned r;
    asm("v_cvt_pk_bf16_f32 %0, %1, %2" : "=v"(r) : "v"(lo), "v"(hi));
    return r;
}

__device__ __forceinline__ s16x8 pack8(f32x4 a, f32x4 b){
    s16x8 r;
#pragma unroll
    for (int i = 0; i < 4; ++i) { r[i] = (short)f2bf(a[i]); r[i+4] = (short)f2bf(b[i]); }
    return r;
}

// XOR swizzle (ushort index into a [rows][64] bf16 tile)
__device__ __forceinline__ int swz(int row, int col){
    return row * 64 + (col ^ ((row & 7) << 3));
}

// direct global->LDS, 16B per lane (dest = uniform base + lane*16)
#define GLOAD_LDS(gp, lp) __builtin_amdgcn_global_load_lds( \
    (const __attribute__((address_space(1))) unsigned int*)(gp), \
    (__attribute__((address_space(3))) unsigned int*)(lp), 16, 0, 0)

// ---------------- workspace layout (bytes) ----------------
#define KBF_OFF   0
#define VTB_OFF   6291456
#define PART_OFF  12582912
#define BMP_OFF   15777792
#define CNT_OFF   15778304
#define WS_NEED   15778432
#define SLOT_F    4160

// ============ kernel 1: convert K,V to swizzled bf16 tiles; bitmap; cnt=0 ============
// 768 WGs = 8 XCDs x 96 (same head->XCD chunks as bb_main's consumers).
__global__ __launch_bounds__(256) void bb_conv(
        const float* __restrict__ k, const float* __restrict__ v,
        const int* __restrict__ mask,
        ushort_t* __restrict__ kbf, ushort_t* __restrict__ vtb,
        u64* __restrict__ bmp, int* __restrict__ cnt)
{
    const int lin = blockIdx.x;
    const int job = (lin & 7) * 96 + (lin >> 3);
    const int h   = job >> 6;
    const int kb  = job & 63;
    const int tid = threadIdx.x;
    __shared__ float vls[64*65];

    if (lin == 0 && tid < 32) cnt[tid] = 0;   // zero split counters every call

    if (h == 0 && tid < 64){
        bool a = mask[(size_t)(kb*64)*SEQ + tid*64] != 0;
        u64 bm = __ballot(a);
        if (tid == 0) bmp[kb] = bm;
    }

    const int j = tid >> 2, c = (tid & 3) * 16;
    const size_t gsrc = (size_t)h*SEQ*DH + (size_t)(kb*64 + j)*DH + c;
    const size_t tdst = ((size_t)h*NB + kb) * 4096;

    {   // K: convert, store swizzled [j][d]
        f32x4 a0 = *(const f32x4*)(k + gsrc);
        f32x4 a1 = *(const f32x4*)(k + gsrc + 4);
        f32x4 a2 = *(const f32x4*)(k + gsrc + 8);
        f32x4 a3 = *(const f32x4*)(k + gsrc + 12);
        *(s16x8*)&kbf[tdst + swz(j, c    )] = pack8(a0, a1);
        *(s16x8*)&kbf[tdst + swz(j, c + 8)] = pack8(a2, a3);
    }
    {   // V: stage fp32 in LDS (padded), transpose, store swizzled [d][j]
        f32x4 b0 = *(const f32x4*)(v + gsrc);
        f32x4 b1 = *(const f32x4*)(v + gsrc + 4);
        f32x4 b2 = *(const f32x4*)(v + gsrc + 8);
        f32x4 b3 = *(const f32x4*)(v + gsrc + 12);
#pragma unroll
        for (int i = 0; i < 4; ++i){
            vls[j*65 + c + i     ] = b0[i];
            vls[j*65 + c + 4 + i ] = b1[i];
            vls[j*65 + c + 8 + i ] = b2[i];
            vls[j*65 + c + 12 + i] = b3[i];
        }
    }
    __syncthreads();
    {
        const int d = tid >> 2, jc = (tid & 3) * 16;
        s16x8 r0, r1;
#pragma unroll
        for (int i = 0; i < 8; ++i){
            r0[i] = (short)f2bf(vls[(jc + i    )*65 + d]);
            r1[i] = (short)f2bf(vls[(jc + i + 8)*65 + d]);
        }
        *(s16x8*)&vtb[tdst + swz(d, jc    )] = r0;
        *(s16x8*)&vtb[tdst + swz(d, jc + 8)] = r1;
    }
}

// ============ kernel 2: swapped-QK^T 32x32 main attention + fused combine ============
// 936 WGs = 8 XCDs x 117 (bijective swizzle). job = h*78 + x:
//   x<62 -> qb=x+1, full k-range, direct out
//   x>=62 -> e=x-62: wq=e>>3 (qb 0 or 63), sp=e&7, 8-block slice -> partial;
//            the LAST of the 8 splitter WGs (device atomic) reduces+stores.
// NOTE: plain __launch_bounds__(256) — the (256,5) variant forced VGPR=48
// and spilled to scratch (R13: 51us, VALUBusy 10%). LDS 32KB caps 5 WG/CU;
// even 4 WG/CU (VGPR<=128) keeps all 936 WGs single-shift (4*256=1024>=936).
__global__ __launch_bounds__(256) void bb_main(
        const float* __restrict__ q,
        const ushort_t* __restrict__ kbf, const ushort_t* __restrict__ vtb,
        const u64* __restrict__ bmp,
        float* __restrict__ out, float* __restrict__ part, int* __restrict__ cnt)
{
    const int lin = blockIdx.x;
    const int job = (lin & 7) * 117 + (lin >> 3);
    const int h   = job / 78;
    const int x   = job - h * 78;

    int qb, wq = -1, sp = 0; u64 rmask;
    if (x < 62) { qb = x + 1; rmask = ~0ull; }
    else { int e = x - 62; wq = e >> 3; sp = e & 7; qb = wq ? 63 : 0; rmask = 0xFFull << (sp*8); }

    const int tid  = threadIdx.x;
    const int wave = tid >> 6;
    const int lane = tid & 63;
    const int l31  = lane & 31;
    const int hi   = lane >> 5;
    const int qh   = wave >> 1;     // q-half (0: rows 0..31, 1: rows 32..63)
    const int kh   = wave & 1;      // k-half within tile (cols kh*32..+31)

    __shared__ __align__(16) ushort_t KV[2][2][4096];   // 32 KB exactly

    const size_t hoff = (size_t)h * SEQ * DH;

    // Q B-fragments (col=q=l31, kk=d), pre-scaled by 0.125*log2(e)
    s16x8 qf[4];
    {
        const float sc = 0.125f * 1.4426950408889634f;
        const float* qp = q + hoff + (size_t)(qb*64 + qh*32 + l31) * DH + 8*hi;
#pragma unroll
        for (int c = 0; c < 4; ++c){
            f32x4 a = *(const f32x4*)(qp + c*16);
            f32x4 b = *(const f32x4*)(qp + c*16 + 4);
            a *= sc; b *= sc;
            qf[c] = pack8(a, b);
        }
    }

    u64 bits = bmp[qb] & rmask;

    const ushort_t* Kb = kbf + (size_t)h * (NB*4096);
    const ushort_t* Vb = vtb + (size_t)h * (NB*4096);

    f32x16 oa0 = {0.f}, oa1 = {0.f};
    float lp = 0.f;

    const int soff = wave*1024 + lane*16;
#define STAGE(gbase, lbase)                                          \
    {                                                                \
        const char* g0 = (const char*)(gbase) + soff;                \
        char*       l0 = (char*)(lbase) + wave*1024;                 \
        GLOAD_LDS(g0, l0);                                           \
        GLOAD_LDS(g0 + 4096, l0 + 4096);                             \
    }

    if (bits){
        const int n = __popcll(bits);
        u64 bpre = bits;

        int kb0 = __builtin_ctzll(bpre); bpre &= bpre - 1;
        STAGE(Kb + (size_t)kb0*4096, &KV[0][0][0]);
        STAGE(Vb + (size_t)kb0*4096, &KV[0][1][0]);

        int buf = 0;
        for (int t = 0; t < n; ++t){
            asm volatile("s_waitcnt vmcnt(0)" ::: "memory");
            __builtin_amdgcn_s_barrier();

            if (bpre){
                int kbn = __builtin_ctzll(bpre); bpre &= bpre - 1;
                STAGE(Kb + (size_t)kbn*4096, &KV[buf^1][0][0]);
                STAGE(Vb + (size_t)kbn*4096, &KV[buf^1][1][0]);
            }

            const ushort_t* Kt = &KV[buf][0][0];
            const ushort_t* Vt = &KV[buf][1][0];

            // S^T = K . Q^T
            f32x16 sa = {0.f};
            __builtin_amdgcn_s_setprio(1);
#pragma unroll
            for (int c = 0; c < 4; ++c){
                s16x8 kf = *(const s16x8*)&Kt[swz(kh*32 + l31, c*16 + 8*hi)];
                sa = __builtin_amdgcn_mfma_f32_32x32x16_bf16(kf, qf[c], sa, 0, 0, 0);
            }
            __builtin_amdgcn_s_setprio(0);

            float p[16];
#pragma unroll
            for (int r = 0; r < 16; ++r){
                p[r] = __builtin_amdgcn_exp2f(sa[r]);
                lp += p[r];
            }

            s16x8 pa[2];
#pragma unroll
            for (int s = 0; s < 2; ++s){
                unsigned a1 = cvtpk(p[8*s+0], p[8*s+1]);
                unsigned b1 = cvtpk(p[8*s+4], p[8*s+5]);
                unsigned a2 = cvtpk(p[8*s+2], p[8*s+3]);
                unsigned b2 = cvtpk(p[8*s+6], p[8*s+7]);
                asm("v_permlane32_swap_b32 %0, %1" : "+v"(a1), "+v"(b1));
                asm("v_permlane32_swap_b32 %0, %1" : "+v"(a2), "+v"(b2));
                union { unsigned w[4]; s16x8 v; } u;
                u.w[0] = a1; u.w[1] = a2; u.w[2] = b1; u.w[3] = b2;
                pa[s] = u.v;
            }

            __builtin_amdgcn_s_setprio(1);
#pragma unroll
            for (int s = 0; s < 2; ++s){
                s16x8 v0 = *(const s16x8*)&Vt[swz(     l31, kh*32 + s*16 + 8*hi)];
                s16x8 v1 = *(const s16x8*)&Vt[swz(32 + l31, kh*32 + s*16 + 8*hi)];
                oa0 = __builtin_amdgcn_mfma_f32_32x32x16_bf16(pa[s], v0, oa0, 0, 0, 0);
                oa1 = __builtin_amdgcn_mfma_f32_32x32x16_bf16(pa[s], v1, oa1, 0, 0, 0);
            }
            __builtin_amdgcn_s_setprio(0);

            buf ^= 1;
        }
    }
#undef STAGE

    // ---- epilogue v2 ----
    float lpf = lp + __shfl_xor(lp, 32);      // l over this wave's 32 k-cols

    __syncthreads();                           // all tile reads done; KV dead
    float* msm = (float*)&KV[0][0][0];         // 4096 f32: merged O (bytes 0..16K)
    float* lsm = (float*)&KV[1][0][0];         // 64 f32: inv/l      (bytes 16K..)
    int*   flg = (int*)  &KV[1][0][128];       // 1 int broadcast slot

    if (kh == 1){
#pragma unroll
        for (int r = 0; r < 16; ++r){
            const int o = (qh*32 + ((r&3) + 8*(r>>2) + 4*hi)) * 64;
            msm[o +      l31] = oa0[r];
            msm[o + 32 + l31] = oa1[r];
        }
        if (lane < 32) lsm[qh*32 + lane] = lpf;
    }
    __syncthreads();

    if (kh == 0){
#pragma unroll
        for (int r = 0; r < 16; ++r){
            const int o = (qh*32 + ((r&3) + 8*(r>>2) + 4*hi)) * 64;
            msm[o +      l31] += oa0[r];
            msm[o + 32 + l31] += oa1[r];
        }
        if (lane < 32){
            float lt = lpf + lsm[qh*32 + lane];
            lsm[qh*32 + lane] = (wq < 0) ? (lt > 0.f ? 1.0f / lt : 0.f) : lt;
        }
    }
    __syncthreads();

    const size_t obase = hoff + (size_t)(qb*64) * DH;   // 16KB-aligned block

    if (wq < 0){
        // dense coalesced out: 4 x dwordx4 per thread, same math as v1
#pragma unroll
        for (int i = 0; i < 4; ++i){
            const int idx = i*1024 + tid*4;
            f32x4 vv = *(const f32x4*)&msm[idx];
            const float iv = lsm[idx >> 6];
            vv *= iv;
            *(f32x4*)&out[obase + idx] = vv;
        }
    } else {
        float* pp = part + ((size_t)(h*2 + wq)*8 + sp) * SLOT_F;
#pragma unroll
        for (int i = 0; i < 4; ++i){
            const int idx = i*1024 + tid*4;
            *(f32x4*)&pp[idx] = *(const f32x4*)&msm[idx];
        }
        if (tid < 64) pp[4096 + tid] = lsm[tid];

        // fused combine: last of the 8 splitters reduces this (h,wq)
        __threadfence();
        if (tid == 0){
            int old = atomicAdd(&cnt[h*2 + wq], 1);
            flg[0] = (old == 7) ? 1 : 0;
        }
        __syncthreads();
        if (flg[0]){
            const float* base = part + (size_t)(h*2 + wq) * 8 * SLOT_F;
            if (tid < 64){
                float s = 0.f;
                for (int s8 = 0; s8 < 8; ++s8) s += base[(size_t)s8*SLOT_F + 4096 + tid];
                lsm[tid] = s > 0.f ? 1.0f / s : 0.f;
            }
            __syncthreads();
#pragma unroll
            for (int i = 0; i < 4; ++i){
                const int idx = i*1024 + tid*4;
                f32x4 acc = {0.f, 0.f, 0.f, 0.f};
                for (int s8 = 0; s8 < 8; ++s8)
                    acc += *(const f32x4*)&base[(size_t)s8*SLOT_F + idx];
                acc *= lsm[idx >> 6];
                *(f32x4*)&out[obase + idx] = acc;
            }
        }
    }
}

// ============ fallback (used if ws too small) ============
__global__ __launch_bounds__(256) void bb_attn_fb(
        const float* __restrict__ q, const float* __restrict__ k,
        const float* __restrict__ v, const int* __restrict__ mask,
        float* __restrict__ out)
{
    const int qb   = blockIdx.x;
    const int h    = blockIdx.y;
    const int tid  = threadIdx.x;
    const int wave = tid >> 6;
    const int lane = tid & 63;
    const int lrow = lane & 15;
    const int lgrp = lane >> 4;

    __shared__ __align__(16) ushort_t Kb[64*64];
    __shared__ __align__(16) ushort_t Vt[64*64];
    __shared__ __align__(16) ushort_t Pw[4][16*64];

    const size_t hoff = (size_t)h * SEQ * DH;
    const int qrow = qb*64 + wave*16 + lrow;
    const float* qp = q + hoff + (size_t)qrow * DH + lgrp*8;
    s16x8 qf[2];
#pragma unroll
    for (int kc = 0; kc < 2; ++kc){
        f32x4 a = *(const f32x4*)(qp + kc*32);
        f32x4 b = *(const f32x4*)(qp + kc*32 + 4);
        a *= 0.125f; b *= 0.125f;
        qf[kc] = pack8(a, b);
    }
    const f32x4 zero = {0.f,0.f,0.f,0.f};
    f32x4 oa[4] = {zero, zero, zero, zero};
    float m_run[4] = {-1e30f,-1e30f,-1e30f,-1e30f};
    float l_run[4] = {0.f,0.f,0.f,0.f};
    const int* mrow = mask + (size_t)(qb*64) * SEQ;
    const int kr  = tid >> 2, kcg  = tid & 3;
    const int j2  = tid >> 3, dgrp = tid & 7;

    for (int kb = 0; kb < NB; ++kb){
        if (mrow[kb*64] == 0) continue;
        __syncthreads();
        {
            const float* kp = k + hoff + (size_t)(kb*64 + kr) * DH + kcg*16;
            f32x4 a0 = *(const f32x4*)(kp);
            f32x4 a1 = *(const f32x4*)(kp+4);
            f32x4 a2 = *(const f32x4*)(kp+8);
            f32x4 a3 = *(const f32x4*)(kp+12);
            *(s16x8*)&Kb[(kr*64) + (kcg*16     ^ ((kr&7)<<3))] = pack8(a0, a1);
            *(s16x8*)&Kb[(kr*64) + ((kcg*16+8) ^ ((kr&7)<<3))] = pack8(a2, a3);
        }
        {
            const float* vp0 = v + hoff + (size_t)(kb*64 + 2*j2) * DH + dgrp*8;
            f32x4 b0 = *(const f32x4*)(vp0);
            f32x4 b1 = *(const f32x4*)(vp0+4);
            f32x4 b2 = *(const f32x4*)(vp0+DH);
            f32x4 b3 = *(const f32x4*)(vp0+DH+4);
            float r0[8] = {b0[0],b0[1],b0[2],b0[3],b1[0],b1[1],b1[2],b1[3]};
            float r1[8] = {b2[0],b2[1],b2[2],b2[3],b3[0],b3[1],b3[2],b3[3]};
#pragma unroll
            for (int i = 0; i < 8; ++i){
                int dd = (i + dgrp) & 7;
                int d  = dgrp*8 + dd;
                unsigned val = (unsigned)f2bf(r0[dd]) | ((unsigned)f2bf(r1[dd]) << 16);
                *(unsigned*)&Vt[(d*64) + (2*j2 ^ ((d&7)<<3))] = val;
            }
        }
        __syncthreads();
        f32x4 sa[4] = {zero, zero, zero, zero};
#pragma unroll
        for (int jt = 0; jt < 4; ++jt)
#pragma unroll
            for (int kc = 0; kc < 2; ++kc){
                int row = jt*16 + lrow, col = kc*32 + lgrp*8;
                s16x8 kf = *(const s16x8*)&Kb[row*64 + (col ^ ((row&7)<<3))];
                sa[jt] = __builtin_amdgcn_mfma_f32_16x16x32_bf16(qf[kc], kf, sa[jt], 0, 0, 0);
            }
        float fac[4];
#pragma unroll
        for (int r = 0; r < 4; ++r){
            float mx = fmaxf(fmaxf(sa[0][r], sa[1][r]), fmaxf(sa[2][r], sa[3][r]));
            mx = fmaxf(mx, __shfl_xor(mx, 1));
            mx = fmaxf(mx, __shfl_xor(mx, 2));
            mx = fmaxf(mx, __shfl_xor(mx, 4));
            mx = fmaxf(mx, __shfl_xor(mx, 8));
            float mn = fmaxf(m_run[r], mx);
            fac[r] = __expf(m_run[r] - mn);
            m_run[r] = mn;
        }
#pragma unroll
        for (int r = 0; r < 4; ++r){
            float p0 = __expf(sa[0][r] - m_run[r]);
            float p1 = __expf(sa[1][r] - m_run[r]);
            float p2 = __expf(sa[2][r] - m_run[r]);
            float p3 = __expf(sa[3][r] - m_run[r]);
            sa[0][r]=p0; sa[1][r]=p1; sa[2][r]=p2; sa[3][r]=p3;
            float sm = p0+p1+p2+p3;
            sm += __shfl_xor(sm, 1);
            sm += __shfl_xor(sm, 2);
            sm += __shfl_xor(sm, 4);
            sm += __shfl_xor(sm, 8);
            l_run[r] = l_run[r]*fac[r] + sm;
        }
#pragma unroll
        for (int dc = 0; dc < 4; ++dc)
#pragma unroll
            for (int r = 0; r < 4; ++r) oa[dc][r] *= fac[r];
#pragma unroll
        for (int jt = 0; jt < 4; ++jt)
#pragma unroll
            for (int r = 0; r < 4; ++r){
                int row = lgrp*4 + r, col = jt*16 + lrow;
                Pw[wave][row*64 + (col ^ ((row&7)<<3))] = f2bf(sa[jt][r]);
            }
        s16x8 pf0 = *(const s16x8*)&Pw[wave][lrow*64 + ((     lgrp*8) ^ ((lrow&7)<<3))];
        s16x8 pf1 = *(const s16x8*)&Pw[wave][lrow*64 + ((32 + lgrp*8) ^ ((lrow&7)<<3))];
#pragma unroll
        for (int dc = 0; dc < 4; ++dc){
            int row0 = dc*16 + lrow;
            s16x8 v0 = *(const s16x8*)&Vt[row0*64 + ((     lgrp*8) ^ ((row0&7)<<3))];
            s16x8 v1 = *(const s16x8*)&Vt[row0*64 + ((32 + lgrp*8) ^ ((row0&7)<<3))];
            oa[dc] = __builtin_amdgcn_mfma_f32_16x16x32_bf16(pf0, v0, oa[dc], 0, 0, 0);
            oa[dc] = __builtin_amdgcn_mfma_f32_16x16x32_bf16(pf1, v1, oa[dc], 0, 0, 0);
        }
    }
    float inv[4];
#pragma unroll
    for (int r = 0; r < 4; ++r) inv[r] = 1.0f / l_run[r];
    float* op = out + hoff + (size_t)(qb*64 + wave*16) * DH;
#pragma unroll
    for (int dc = 0; dc < 4; ++dc)
#pragma unroll
        for (int r = 0; r < 4; ++r)
            op[(size_t)(lgrp*4 + r) * DH + dc*16 + lrow] = oa[dc][r] * inv[r];
}

extern "C" void kernel_launch(void* const* d_in, const int* in_sizes, int n_in,
                              void* d_out, int out_size, void* d_ws, size_t ws_size,
                              hipStream_t stream)
{
    const float* q    = (const float*)d_in[0];
    const float* k    = (const float*)d_in[1];
    const float* v    = (const float*)d_in[2];
    const int*   mask = (const int*)d_in[3];
    float* out = (float*)d_out;

    if (ws_size < (size_t)WS_NEED){
        dim3 grid(NB, NH, 1);
        bb_attn_fb<<<grid, 256, 0, stream>>>(q, k, v, mask, out);
        return;
    }

    char* ws = (char*)d_ws;
    ushort_t* kbf = (ushort_t*)(ws + KBF_OFF);
    ushort_t* vtb = (ushort_t*)(ws + VTB_OFF);
    float*    prt = (float*)   (ws + PART_OFF);
    u64*      bmp = (u64*)     (ws + BMP_OFF);
    int*      cnt = (int*)     (ws + CNT_OFF);

    bb_conv<<<dim3(768, 1, 1), 256, 0, stream>>>(k, v, mask, kbf, vtb, bmp, cnt);
    bb_main<<<dim3(936, 1, 1), 256, 0, stream>>>(q, kbf, vtb, bmp, out, prt, cnt);
}

// Round 15
// 36.598 us; speedup vs baseline: 1.6707x; 1.6707x over previous
//
#include <hip/hip_runtime.h>
#include <stdint.h>

#define SEQ 4096
#define DH  64
#define NB  64
#define NH  12

typedef float  f32x4   __attribute__((ext_vector_type(4)));
typedef float  f32x16  __attribute__((ext_vector_type(16)));
typedef short  s16x8   __attribute__((ext_vector_type(8)));
typedef unsigned short ushort_t;
typedef unsigned long long u64;

__device__ __forceinline__ unsigned short f2bf(float x){
    union { float f; unsigned u; } c; c.f = x;
    unsigned u = c.u;
    u += 0x7fffu + ((u >> 16) & 1u);   // round-to-nearest-even
    return (unsigned short)(u >> 16);
}

__device__ __forceinline__ unsigned cvtpk(float lo, float hi){
    unsigned r;
    asm("v_cvt_pk_bf16_f32 %0, %1, %2" : "=v"(r) : "v"(lo), "v"(hi));
    return r;
}

__device__ __forceinline__ s16x8 pack8(f32x4 a, f32x4 b){
    s16x8 r;
#pragma unroll
    for (int i = 0; i < 4; ++i) { r[i] = (short)f2bf(a[i]); r[i+4] = (short)f2bf(b[i]); }
    return r;
}

// XOR swizzle (ushort index into a [rows][64] bf16 tile)
__device__ __forceinline__ int swz(int row, int col){
    return row * 64 + (col ^ ((row & 7) << 3));
}

// direct global->LDS, 16B per lane (dest = uniform base + lane*16)
#define GLOAD_LDS(gp, lp) __builtin_amdgcn_global_load_lds( \
    (const __attribute__((address_space(1))) unsigned int*)(gp), \
    (__attribute__((address_space(3))) unsigned int*)(lp), 16, 0, 0)

// ---------------- workspace layout (bytes) ----------------
#define KBF_OFF   0
#define VTB_OFF   6291456
#define PART_OFF  12582912
#define BMP_OFF   15777792
#define WS_NEED   15778304
#define SLOT_F    4160

// ============ kernel 1: convert K,V to swizzled bf16 tiles; bitmap ============
// 768 WGs = 8 XCDs x 96 (same head->XCD chunks as bb_main's consumers).
__global__ __launch_bounds__(256) void bb_conv(
        const float* __restrict__ k, const float* __restrict__ v,
        const int* __restrict__ mask,
        ushort_t* __restrict__ kbf, ushort_t* __restrict__ vtb,
        u64* __restrict__ bmp)
{
    const int lin = blockIdx.x;
    const int job = (lin & 7) * 96 + (lin >> 3);
    const int h   = job >> 6;
    const int kb  = job & 63;
    const int tid = threadIdx.x;
    __shared__ float vls[64*65];

    if (h == 0 && tid < 64){
        bool a = mask[(size_t)(kb*64)*SEQ + tid*64] != 0;
        u64 bm = __ballot(a);
        if (tid == 0) bmp[kb] = bm;
    }

    const int j = tid >> 2, c = (tid & 3) * 16;
    const size_t gsrc = (size_t)h*SEQ*DH + (size_t)(kb*64 + j)*DH + c;
    const size_t tdst = ((size_t)h*NB + kb) * 4096;

    {   // K: convert, store swizzled [j][d]
        f32x4 a0 = *(const f32x4*)(k + gsrc);
        f32x4 a1 = *(const f32x4*)(k + gsrc + 4);
        f32x4 a2 = *(const f32x4*)(k + gsrc + 8);
        f32x4 a3 = *(const f32x4*)(k + gsrc + 12);
        *(s16x8*)&kbf[tdst + swz(j, c    )] = pack8(a0, a1);
        *(s16x8*)&kbf[tdst + swz(j, c + 8)] = pack8(a2, a3);
    }
    {   // V: stage fp32 in LDS (padded), transpose, store swizzled [d][j]
        f32x4 b0 = *(const f32x4*)(v + gsrc);
        f32x4 b1 = *(const f32x4*)(v + gsrc + 4);
        f32x4 b2 = *(const f32x4*)(v + gsrc + 8);
        f32x4 b3 = *(const f32x4*)(v + gsrc + 12);
#pragma unroll
        for (int i = 0; i < 4; ++i){
            vls[j*65 + c + i     ] = b0[i];
            vls[j*65 + c + 4 + i ] = b1[i];
            vls[j*65 + c + 8 + i ] = b2[i];
            vls[j*65 + c + 12 + i] = b3[i];
        }
    }
    __syncthreads();
    {
        const int d = tid >> 2, jc = (tid & 3) * 16;
        s16x8 r0, r1;
#pragma unroll
        for (int i = 0; i < 8; ++i){
            r0[i] = (short)f2bf(vls[(jc + i    )*65 + d]);
            r1[i] = (short)f2bf(vls[(jc + i + 8)*65 + d]);
        }
        *(s16x8*)&vtb[tdst + swz(d, jc    )] = r0;
        *(s16x8*)&vtb[tdst + swz(d, jc + 8)] = r1;
    }
}

// ============ kernel 2: swapped-QK^T 32x32 main attention ============
// EXACT R11 structure (best measured 36.3us total) with ONE change:
// epilogue v2 — merge k-halves in LDS, then ALL 256 threads store the 16KB
// output block densely (4 x dwordx4 each) instead of 2 waves x 32 scattered
// dwords. Bit-identical output (commutative fp32 add, same mul order).
// NO atomics / NO __threadfence (R13's fusion regressed main 20->55us).
__global__ __launch_bounds__(256) void bb_main(
        const float* __restrict__ q,
        const ushort_t* __restrict__ kbf, const ushort_t* __restrict__ vtb,
        const u64* __restrict__ bmp,
        float* __restrict__ out, float* __restrict__ part)
{
    const int lin = blockIdx.x;
    const int job = (lin & 7) * 117 + (lin >> 3);
    const int h   = job / 78;
    const int x   = job - h * 78;

    int qb, wq = -1, sp = 0; u64 rmask;
    if (x < 62) { qb = x + 1; rmask = ~0ull; }
    else { int e = x - 62; wq = e >> 3; sp = e & 7; qb = wq ? 63 : 0; rmask = 0xFFull << (sp*8); }

    const int tid  = threadIdx.x;
    const int wave = tid >> 6;
    const int lane = tid & 63;
    const int l31  = lane & 31;
    const int hi   = lane >> 5;
    const int qh   = wave >> 1;     // q-half (0: rows 0..31, 1: rows 32..63)
    const int kh   = wave & 1;      // k-half within tile (cols kh*32..+31)

    __shared__ __align__(16) ushort_t KV[2][2][4096];   // 32 KB
    __shared__ float lsm[64];

    const size_t hoff = (size_t)h * SEQ * DH;

    // Q B-fragments (col=q=l31, kk=d), pre-scaled by 0.125*log2(e)
    s16x8 qf[4];
    {
        const float sc = 0.125f * 1.4426950408889634f;
        const float* qp = q + hoff + (size_t)(qb*64 + qh*32 + l31) * DH + 8*hi;
#pragma unroll
        for (int c = 0; c < 4; ++c){
            f32x4 a = *(const f32x4*)(qp + c*16);
            f32x4 b = *(const f32x4*)(qp + c*16 + 4);
            a *= sc; b *= sc;
            qf[c] = pack8(a, b);
        }
    }

    u64 bits = bmp[qb] & rmask;

    const ushort_t* Kb = kbf + (size_t)h * (NB*4096);
    const ushort_t* Vb = vtb + (size_t)h * (NB*4096);

    f32x16 oa0 = {0.f}, oa1 = {0.f};
    float lp = 0.f;

    const int soff = wave*1024 + lane*16;
#define STAGE(gbase, lbase)                                          \
    {                                                                \
        const char* g0 = (const char*)(gbase) + soff;                \
        char*       l0 = (char*)(lbase) + wave*1024;                 \
        GLOAD_LDS(g0, l0);                                           \
        GLOAD_LDS(g0 + 4096, l0 + 4096);                             \
    }

    if (bits){
        const int n = __popcll(bits);
        u64 bpre = bits;

        int kb0 = __builtin_ctzll(bpre); bpre &= bpre - 1;
        STAGE(Kb + (size_t)kb0*4096, &KV[0][0][0]);
        STAGE(Vb + (size_t)kb0*4096, &KV[0][1][0]);

        int buf = 0;
        for (int t = 0; t < n; ++t){
            // our own stage(t) loads are the only outstanding VM ops
            asm volatile("s_waitcnt vmcnt(0)" ::: "memory");
            __builtin_amdgcn_s_barrier();   // stage(t) landed; reads of buf^1 done

            if (bpre){
                int kbn = __builtin_ctzll(bpre); bpre &= bpre - 1;
                STAGE(Kb + (size_t)kbn*4096, &KV[buf^1][0][0]);
                STAGE(Vb + (size_t)kbn*4096, &KV[buf^1][1][0]);
            }

            const ushort_t* Kt = &KV[buf][0][0];
            const ushort_t* Vt = &KV[buf][1][0];

            // S^T = K . Q^T : A=K[j=kh*32+l31][d-chunk], B=Q
            f32x16 sa = {0.f};
            __builtin_amdgcn_s_setprio(1);
#pragma unroll
            for (int c = 0; c < 4; ++c){
                s16x8 kf = *(const s16x8*)&Kt[swz(kh*32 + l31, c*16 + 8*hi)];
                sa = __builtin_amdgcn_mfma_f32_32x32x16_bf16(kf, qf[c], sa, 0, 0, 0);
            }
            __builtin_amdgcn_s_setprio(0);

            // p = 2^sa (Q carried the log2e factor); lane-local l accumulation
            float p[16];
#pragma unroll
            for (int r = 0; r < 16; ++r){
                p[r] = __builtin_amdgcn_exp2f(sa[r]);
                lp += p[r];
            }

            // P -> bf16 PV A-frags: v_cvt_pk_bf16_f32 + permlane32_swap
            s16x8 pa[2];
#pragma unroll
            for (int s = 0; s < 2; ++s){
                unsigned a1 = cvtpk(p[8*s+0], p[8*s+1]);
                unsigned b1 = cvtpk(p[8*s+4], p[8*s+5]);
                unsigned a2 = cvtpk(p[8*s+2], p[8*s+3]);
                unsigned b2 = cvtpk(p[8*s+6], p[8*s+7]);
                asm("v_permlane32_swap_b32 %0, %1" : "+v"(a1), "+v"(b1));
                asm("v_permlane32_swap_b32 %0, %1" : "+v"(a2), "+v"(b2));
                union { unsigned w[4]; s16x8 v; } u;
                u.w[0] = a1; u.w[1] = a2; u.w[2] = b1; u.w[3] = b2;
                pa[s] = u.v;
            }

            // O += P V : A=pa (row=q=l31, kk=j), B=V^T (col=d, kk=j)
            __builtin_amdgcn_s_setprio(1);
#pragma unroll
            for (int s = 0; s < 2; ++s){
                s16x8 v0 = *(const s16x8*)&Vt[swz(     l31, kh*32 + s*16 + 8*hi)];
                s16x8 v1 = *(const s16x8*)&Vt[swz(32 + l31, kh*32 + s*16 + 8*hi)];
                oa0 = __builtin_amdgcn_mfma_f32_32x32x16_bf16(pa[s], v0, oa0, 0, 0, 0);
                oa1 = __builtin_amdgcn_mfma_f32_32x32x16_bf16(pa[s], v1, oa1, 0, 0, 0);
            }
            __builtin_amdgcn_s_setprio(0);

            buf ^= 1;
        }
    }
#undef STAGE

    // ---- epilogue v2 (dense stores; no atomics) ----
    float lpf = lp + __shfl_xor(lp, 32);      // l over this wave's 32 k-cols

    __syncthreads();                           // all tile reads done; KV dead
    float* msm = (float*)&KV[0][0][0];         // 4096 f32: merged O (16 KB)

    if (kh == 1){
#pragma unroll
        for (int r = 0; r < 16; ++r){
            const int o = (qh*32 + ((r&3) + 8*(r>>2) + 4*hi)) * 64;
            msm[o +      l31] = oa0[r];
            msm[o + 32 + l31] = oa1[r];
        }
        if (lane < 32) lsm[qh*32 + lane] = lpf;
    }
    __syncthreads();

    if (kh == 0){
#pragma unroll
        for (int r = 0; r < 16; ++r){
            const int o = (qh*32 + ((r&3) + 8*(r>>2) + 4*hi)) * 64;
            msm[o +      l31] += oa0[r];
            msm[o + 32 + l31] += oa1[r];
        }
        if (lane < 32){
            float lt = lpf + lsm[qh*32 + lane];
            lsm[qh*32 + lane] = (wq < 0) ? (lt > 0.f ? 1.0f / lt : 0.f) : lt;
        }
    }
    __syncthreads();

    const size_t obase = hoff + (size_t)(qb*64) * DH;   // 16KB output block

    if (wq < 0){
#pragma unroll
        for (int i = 0; i < 4; ++i){
            const int idx = i*1024 + tid*4;
            f32x4 vv = *(const f32x4*)&msm[idx];
            vv *= lsm[idx >> 6];
            *(f32x4*)&out[obase + idx] = vv;
        }
    } else {
        float* pp = part + ((size_t)(h*2 + wq)*8 + sp) * SLOT_F;
#pragma unroll
        for (int i = 0; i < 4; ++i){
            const int idx = i*1024 + tid*4;
            *(f32x4*)&pp[idx] = *(const f32x4*)&msm[idx];
        }
        if (tid < 64) pp[4096 + tid] = lsm[tid];
    }
}

// ============ kernel 3: combine split partials for qb in {0,63} ============
__global__ __launch_bounds__(256) void bb_comb(
        const float* __restrict__ part, float* __restrict__ out)
{
    const int h = blockIdx.x >> 1, wq = blockIdx.x & 1;
    const int qb = wq ? 63 : 0;
    const int tid = threadIdx.x;
    const int i = tid >> 2, cg = (tid & 3) * 16;

    const float* base = part + (size_t)(h*2 + wq) * 8 * SLOT_F;
    f32x4 acc[4] = {{0,0,0,0},{0,0,0,0},{0,0,0,0},{0,0,0,0}};
    float ls = 0.f;
#pragma unroll
    for (int s = 0; s < 8; ++s){
        const float* p = base + (size_t)s * SLOT_F;
#pragma unroll
        for (int c4 = 0; c4 < 4; ++c4)
            acc[c4] += *(const f32x4*)(p + (size_t)i*DH + cg + c4*4);
        ls += p[4096 + i];
    }
    const float inv = ls > 0.f ? 1.0f / ls : 0.f;
    float* op = out + (size_t)h*SEQ*DH + (size_t)(qb*64 + i)*DH + cg;
#pragma unroll
    for (int c4 = 0; c4 < 4; ++c4){
        f32x4 r = acc[c4] * inv;
        *(f32x4*)(op + c4*4) = r;
    }
}

// ============ fallback (used if ws too small) ============
__global__ __launch_bounds__(256) void bb_attn_fb(
        const float* __restrict__ q, const float* __restrict__ k,
        const float* __restrict__ v, const int* __restrict__ mask,
        float* __restrict__ out)
{
    const int qb   = blockIdx.x;
    const int h    = blockIdx.y;
    const int tid  = threadIdx.x;
    const int wave = tid >> 6;
    const int lane = tid & 63;
    const int lrow = lane & 15;
    const int lgrp = lane >> 4;

    __shared__ __align__(16) ushort_t Kb[64*64];
    __shared__ __align__(16) ushort_t Vt[64*64];
    __shared__ __align__(16) ushort_t Pw[4][16*64];

    const size_t hoff = (size_t)h * SEQ * DH;
    const int qrow = qb*64 + wave*16 + lrow;
    const float* qp = q + hoff + (size_t)qrow * DH + lgrp*8;
    s16x8 qf[2];
#pragma unroll
    for (int kc = 0; kc < 2; ++kc){
        f32x4 a = *(const f32x4*)(qp + kc*32);
        f32x4 b = *(const f32x4*)(qp + kc*32 + 4);
        a *= 0.125f; b *= 0.125f;
        qf[kc] = pack8(a, b);
    }
    const f32x4 zero = {0.f,0.f,0.f,0.f};
    f32x4 oa[4] = {zero, zero, zero, zero};
    float m_run[4] = {-1e30f,-1e30f,-1e30f,-1e30f};
    float l_run[4] = {0.f,0.f,0.f,0.f};
    const int* mrow = mask + (size_t)(qb*64) * SEQ;
    const int kr  = tid >> 2, kcg  = tid & 3;
    const int j2  = tid >> 3, dgrp = tid & 7;

    for (int kb = 0; kb < NB; ++kb){
        if (mrow[kb*64] == 0) continue;
        __syncthreads();
        {
            const float* kp = k + hoff + (size_t)(kb*64 + kr) * DH + kcg*16;
            f32x4 a0 = *(const f32x4*)(kp);
            f32x4 a1 = *(const f32x4*)(kp+4);
            f32x4 a2 = *(const f32x4*)(kp+8);
            f32x4 a3 = *(const f32x4*)(kp+12);
            *(s16x8*)&Kb[(kr*64) + (kcg*16     ^ ((kr&7)<<3))] = pack8(a0, a1);
            *(s16x8*)&Kb[(kr*64) + ((kcg*16+8) ^ ((kr&7)<<3))] = pack8(a2, a3);
        }
        {
            const float* vp0 = v + hoff + (size_t)(kb*64 + 2*j2) * DH + dgrp*8;
            f32x4 b0 = *(const f32x4*)(vp0);
            f32x4 b1 = *(const f32x4*)(vp0+4);
            f32x4 b2 = *(const f32x4*)(vp0+DH);
            f32x4 b3 = *(const f32x4*)(vp0+DH+4);
            float r0[8] = {b0[0],b0[1],b0[2],b0[3],b1[0],b1[1],b1[2],b1[3]};
            float r1[8] = {b2[0],b2[1],b2[2],b2[3],b3[0],b3[1],b3[2],b3[3]};
#pragma unroll
            for (int i = 0; i < 8; ++i){
                int dd = (i + dgrp) & 7;
                int d  = dgrp*8 + dd;
                unsigned val = (unsigned)f2bf(r0[dd]) | ((unsigned)f2bf(r1[dd]) << 16);
                *(unsigned*)&Vt[(d*64) + (2*j2 ^ ((d&7)<<3))] = val;
            }
        }
        __syncthreads();
        f32x4 sa[4] = {zero, zero, zero, zero};
#pragma unroll
        for (int jt = 0; jt < 4; ++jt)
#pragma unroll
            for (int kc = 0; kc < 2; ++kc){
                int row = jt*16 + lrow, col = kc*32 + lgrp*8;
                s16x8 kf = *(const s16x8*)&Kb[row*64 + (col ^ ((row&7)<<3))];
                sa[jt] = __builtin_amdgcn_mfma_f32_16x16x32_bf16(qf[kc], kf, sa[jt], 0, 0, 0);
            }
        float fac[4];
#pragma unroll
        for (int r = 0; r < 4; ++r){
            float mx = fmaxf(fmaxf(sa[0][r], sa[1][r]), fmaxf(sa[2][r], sa[3][r]));
            mx = fmaxf(mx, __shfl_xor(mx, 1));
            mx = fmaxf(mx, __shfl_xor(mx, 2));
            mx = fmaxf(mx, __shfl_xor(mx, 4));
            mx = fmaxf(mx, __shfl_xor(mx, 8));
            float mn = fmaxf(m_run[r], mx);
            fac[r] = __expf(m_run[r] - mn);
            m_run[r] = mn;
        }
#pragma unroll
        for (int r = 0; r < 4; ++r){
            float p0 = __expf(sa[0][r] - m_run[r]);
            float p1 = __expf(sa[1][r] - m_run[r]);
            float p2 = __expf(sa[2][r] - m_run[r]);
            float p3 = __expf(sa[3][r] - m_run[r]);
            sa[0][r]=p0; sa[1][r]=p1; sa[2][r]=p2; sa[3][r]=p3;
            float sm = p0+p1+p2+p3;
            sm += __shfl_xor(sm, 1);
            sm += __shfl_xor(sm, 2);
            sm += __shfl_xor(sm, 4);
            sm += __shfl_xor(sm, 8);
            l_run[r] = l_run[r]*fac[r] + sm;
        }
#pragma unroll
        for (int dc = 0; dc < 4; ++dc)
#pragma unroll
            for (int r = 0; r < 4; ++r) oa[dc][r] *= fac[r];
#pragma unroll
        for (int jt = 0; jt < 4; ++jt)
#pragma unroll
            for (int r = 0; r < 4; ++r){
                int row = lgrp*4 + r, col = jt*16 + lrow;
                Pw[wave][row*64 + (col ^ ((row&7)<<3))] = f2bf(sa[jt][r]);
            }
        s16x8 pf0 = *(const s16x8*)&Pw[wave][lrow*64 + ((     lgrp*8) ^ ((lrow&7)<<3))];
        s16x8 pf1 = *(const s16x8*)&Pw[wave][lrow*64 + ((32 + lgrp*8) ^ ((lrow&7)<<3))];
#pragma unroll
        for (int dc = 0; dc < 4; ++dc){
            int row0 = dc*16 + lrow;
            s16x8 v0 = *(const s16x8*)&Vt[row0*64 + ((     lgrp*8) ^ ((row0&7)<<3))];
            s16x8 v1 = *(const s16x8*)&Vt[row0*64 + ((32 + lgrp*8) ^ ((row0&7)<<3))];
            oa[dc] = __builtin_amdgcn_mfma_f32_16x16x32_bf16(pf0, v0, oa[dc], 0, 0, 0);
            oa[dc] = __builtin_amdgcn_mfma_f32_16x16x32_bf16(pf1, v1, oa[dc], 0, 0, 0);
        }
    }
    float inv[4];
#pragma unroll
    for (int r = 0; r < 4; ++r) inv[r] = 1.0f / l_run[r];
    float* op = out + hoff + (size_t)(qb*64 + wave*16) * DH;
#pragma unroll
    for (int dc = 0; dc < 4; ++dc)
#pragma unroll
        for (int r = 0; r < 4; ++r)
            op[(size_t)(lgrp*4 + r) * DH + dc*16 + lrow] = oa[dc][r] * inv[r];
}

extern "C" void kernel_launch(void* const* d_in, const int* in_sizes, int n_in,
                              void* d_out, int out_size, void* d_ws, size_t ws_size,
                              hipStream_t stream)
{
    const float* q    = (const float*)d_in[0];
    const float* k    = (const float*)d_in[1];
    const float* v    = (const float*)d_in[2];
    const int*   mask = (const int*)d_in[3];
    float* out = (float*)d_out;

    if (ws_size < (size_t)WS_NEED){
        dim3 grid(NB, NH, 1);
        bb_attn_fb<<<grid, 256, 0, stream>>>(q, k, v, mask, out);
        return;
    }

    char* ws = (char*)d_ws;
    ushort_t* kbf = (ushort_t*)(ws + KBF_OFF);
    ushort_t* vtb = (ushort_t*)(ws + VTB_OFF);
    float*    prt = (float*)   (ws + PART_OFF);
    u64*      bmp = (u64*)     (ws + BMP_OFF);

    bb_conv<<<dim3(768, 1, 1), 256, 0, stream>>>(k, v, mask, kbf, vtb, bmp);
    bb_main<<<dim3(936, 1, 1), 256, 0, stream>>>(q, kbf, vtb, bmp, out, prt);
    bb_comb<<<dim3(24, 1, 1), 256, 0, stream>>>(prt, out);
}

// Round 16
// 36.137 us; speedup vs baseline: 1.6920x; 1.0128x over previous
//
#include <hip/hip_runtime.h>
#include <stdint.h>

#define SEQ 4096
#define DH  64
#define NB  64
#define NH  12

typedef float  f32x4   __attribute__((ext_vector_type(4)));
typedef float  f32x16  __attribute__((ext_vector_type(16)));
typedef short  s16x8   __attribute__((ext_vector_type(8)));
typedef unsigned short ushort_t;
typedef unsigned long long u64;

__device__ __forceinline__ unsigned short f2bf(float x){
    union { float f; unsigned u; } c; c.f = x;
    unsigned u = c.u;
    u += 0x7fffu + ((u >> 16) & 1u);   // round-to-nearest-even
    return (unsigned short)(u >> 16);
}

__device__ __forceinline__ unsigned cvtpk(float lo, float hi){
    unsigned r;
    asm("v_cvt_pk_bf16_f32 %0, %1, %2" : "=v"(r) : "v"(lo), "v"(hi));
    return r;
}

__device__ __forceinline__ s16x8 pack8(f32x4 a, f32x4 b){
    s16x8 r;
#pragma unroll
    for (int i = 0; i < 4; ++i) { r[i] = (short)f2bf(a[i]); r[i+4] = (short)f2bf(b[i]); }
    return r;
}

// XOR swizzle (ushort index into a [rows][64] bf16 tile) — used for K only.
__device__ __forceinline__ int swz(int row, int col){
    return row * 64 + (col ^ ((row & 7) << 3));
}

// direct global->LDS, 16B per lane (dest = uniform base + lane*16)
#define GLOAD_LDS(gp, lp) __builtin_amdgcn_global_load_lds( \
    (const __attribute__((address_space(1))) unsigned int*)(gp), \
    (__attribute__((address_space(3))) unsigned int*)(lp), 16, 0, 0)

// ---------------- workspace layout (bytes) ----------------
#define KBF_OFF   0
#define VTB_OFF   6291456
#define PART_OFF  12582912
#define BMP_OFF   15777792
#define WS_NEED   15778304
#define SLOT_F    4160

// ============ kernel 1: convert K,V to bf16 tiles; bitmap ============
// K: swizzled [j][d] (staged via global_load_lds in main).
// V: FRAGMENT-MAJOR layout — fragment f = kh*4 + s*2 + (d>>5), lane slot
// = hi*32 + (d&31), 8 ushorts (j elems) per slot. Main loads each PV
// B-fragment as ONE coalesced 1KB global_load_dwordx4 (no LDS for V).
// 768 WGs = 8 XCDs x 96 (same head->XCD chunks as bb_main's consumers).
__global__ __launch_bounds__(256) void bb_conv(
        const float* __restrict__ k, const float* __restrict__ v,
        const int* __restrict__ mask,
        ushort_t* __restrict__ kbf, ushort_t* __restrict__ vtb,
        u64* __restrict__ bmp)
{
    const int lin = blockIdx.x;
    const int job = (lin & 7) * 96 + (lin >> 3);
    const int h   = job >> 6;
    const int kb  = job & 63;
    const int tid = threadIdx.x;
    __shared__ float vls[64*65];

    if (h == 0 && tid < 64){
        bool a = mask[(size_t)(kb*64)*SEQ + tid*64] != 0;
        u64 bm = __ballot(a);
        if (tid == 0) bmp[kb] = bm;
    }

    const int j = tid >> 2, c = (tid & 3) * 16;
    const size_t gsrc = (size_t)h*SEQ*DH + (size_t)(kb*64 + j)*DH + c;
    const size_t tdst = ((size_t)h*NB + kb) * 4096;

    {   // K: convert, store swizzled [j][d]
        f32x4 a0 = *(const f32x4*)(k + gsrc);
        f32x4 a1 = *(const f32x4*)(k + gsrc + 4);
        f32x4 a2 = *(const f32x4*)(k + gsrc + 8);
        f32x4 a3 = *(const f32x4*)(k + gsrc + 12);
        *(s16x8*)&kbf[tdst + swz(j, c    )] = pack8(a0, a1);
        *(s16x8*)&kbf[tdst + swz(j, c + 8)] = pack8(a2, a3);
    }
    {   // V: stage fp32 in LDS (padded), transpose
        f32x4 b0 = *(const f32x4*)(v + gsrc);
        f32x4 b1 = *(const f32x4*)(v + gsrc + 4);
        f32x4 b2 = *(const f32x4*)(v + gsrc + 8);
        f32x4 b3 = *(const f32x4*)(v + gsrc + 12);
#pragma unroll
        for (int i = 0; i < 4; ++i){
            vls[j*65 + c + i     ] = b0[i];
            vls[j*65 + c + 4 + i ] = b1[i];
            vls[j*65 + c + 8 + i ] = b2[i];
            vls[j*65 + c + 12 + i] = b3[i];
        }
    }
    __syncthreads();
    {
        const int d = tid >> 2, jc = (tid & 3) * 16;
        s16x8 r0, r1;
#pragma unroll
        for (int i = 0; i < 8; ++i){
            r0[i] = (short)f2bf(vls[(jc + i    )*65 + d]);   // j = jc..jc+7
            r1[i] = (short)f2bf(vls[(jc + i + 8)*65 + d]);   // j = jc+8..jc+15
        }
        // fragment-major: f = (jc>>5)*4 + ((jc>>4)&1)*2 + (d>>5)
        const int f0 = ((jc >> 5) << 2) + (((jc >> 4) & 1) << 1) + (d >> 5);
        *(s16x8*)&vtb[tdst + f0*512 +       (d & 31)*8] = r0;  // hi=0 slot
        *(s16x8*)&vtb[tdst + f0*512 + 256 + (d & 31)*8] = r1;  // hi=1 slot
    }
}

// ============ kernel 2: swapped-QK^T 32x32 main attention ============
// 936 WGs = 8 XCDs x 117 (bijective swizzle). job = h*78 + x:
//   x<62 -> qb=x+1, full k-range, direct out
//   x>=62 -> e=x-62: wq=e>>3 (qb 0 or 63), sp=e&7, 8-block slice -> partial
// K-only LDS double buffer (16 KB). V fragments loaded DIRECTLY from global
// (fragment-major vtb; 4 coalesced 1KB loads/iter) issued right after the
// barrier — latency hides under QK^T + softmax (T14). Per-iter LDS traffic
// halves: 8KB stage + 16KB read vs 16+32 before. Dummy K-stage keeps vmcnt
// uniform. Bit-identical output to R15.
__global__ __launch_bounds__(256) void bb_main(
        const float* __restrict__ q,
        const ushort_t* __restrict__ kbf, const ushort_t* __restrict__ vtb,
        const u64* __restrict__ bmp,
        float* __restrict__ out, float* __restrict__ part)
{
    const int lin = blockIdx.x;
    const int job = (lin & 7) * 117 + (lin >> 3);
    const int h   = job / 78;
    const int x   = job - h * 78;

    int qb, wq = -1, sp = 0; u64 rmask;
    if (x < 62) { qb = x + 1; rmask = ~0ull; }
    else { int e = x - 62; wq = e >> 3; sp = e & 7; qb = wq ? 63 : 0; rmask = 0xFFull << (sp*8); }

    const int tid  = threadIdx.x;
    const int wave = tid >> 6;
    const int lane = tid & 63;
    const int l31  = lane & 31;
    const int hi   = lane >> 5;
    const int qh   = wave >> 1;     // q-half (0: rows 0..31, 1: rows 32..63)
    const int kh   = wave & 1;      // k-half within tile (cols kh*32..+31)

    __shared__ __align__(16) ushort_t KV[2][4096];   // K double buffer, 16 KB
    __shared__ float lsm[64];

    const size_t hoff = (size_t)h * SEQ * DH;

    // Q B-fragments (col=q=l31, kk=d), pre-scaled by 0.125*log2(e)
    s16x8 qf[4];
    {
        const float sc = 0.125f * 1.4426950408889634f;
        const float* qp = q + hoff + (size_t)(qb*64 + qh*32 + l31) * DH + 8*hi;
#pragma unroll
        for (int c = 0; c < 4; ++c){
            f32x4 a = *(const f32x4*)(qp + c*16);
            f32x4 b = *(const f32x4*)(qp + c*16 + 4);
            a *= sc; b *= sc;
            qf[c] = pack8(a, b);
        }
    }

    u64 bits = bmp[qb] & rmask;

    const ushort_t* Kb = kbf + (size_t)h * (NB*4096);
    const ushort_t* Vb = vtb + (size_t)h * (NB*4096);

    f32x16 oa0 = {0.f}, oa1 = {0.f};
    float lp = 0.f;

    const int soff = wave*1024 + lane*16;
#define STAGE(gbase, lbase)                                          \
    {                                                                \
        const char* g0 = (const char*)(gbase) + soff;                \
        char*       l0 = (char*)(lbase) + wave*1024;                 \
        GLOAD_LDS(g0, l0);                                           \
        GLOAD_LDS(g0 + 4096, l0 + 4096);                             \
    }

    if (bits){
        const int n = __popcll(bits);
        u64 rem = bits;

        const int kb0 = __builtin_ctzll(rem); rem &= rem - 1;
        STAGE(Kb + (size_t)kb0*4096, &KV[0][0]);

        int kb_cur = kb0;
        int buf = 0;
        for (int t = 0; t < n; ++t){
            // our own K-stage(t) loads are the only outstanding VM ops
            asm volatile("s_waitcnt vmcnt(0)" ::: "memory");
            __builtin_amdgcn_s_barrier();   // K(t) landed; reads of buf^1 done

            // V fragments for tile t: 4 coalesced 1KB loads (consumed at PV)
            const ushort_t* vp = Vb + (size_t)kb_cur*4096 + kh*2048 + lane*8;
            s16x8 vf00 = *(const s16x8*)(vp       );   // s0, d 0..31
            s16x8 vf01 = *(const s16x8*)(vp +  512);   // s0, d 32..63
            s16x8 vf10 = *(const s16x8*)(vp + 1024);   // s1, d 0..31
            s16x8 vf11 = *(const s16x8*)(vp + 1536);   // s1, d 32..63

            // stage next K (dummy = kb0 when exhausted; never read then)
            int kbn = kb0;
            if (rem){ kbn = __builtin_ctzll(rem); rem &= rem - 1; }
            STAGE(Kb + (size_t)kbn*4096, &KV[buf^1][0]);

            const ushort_t* Kt = &KV[buf][0];

            // S^T = K . Q^T : A=K[j=kh*32+l31][d-chunk], B=Q
            f32x16 sa = {0.f};
            __builtin_amdgcn_s_setprio(1);
#pragma unroll
            for (int c = 0; c < 4; ++c){
                s16x8 kf = *(const s16x8*)&Kt[swz(kh*32 + l31, c*16 + 8*hi)];
                sa = __builtin_amdgcn_mfma_f32_32x32x16_bf16(kf, qf[c], sa, 0, 0, 0);
            }
            __builtin_amdgcn_s_setprio(0);

            // p = 2^sa (Q carried the log2e factor); lane-local l accumulation
            float p[16];
#pragma unroll
            for (int r = 0; r < 16; ++r){
                p[r] = __builtin_amdgcn_exp2f(sa[r]);
                lp += p[r];
            }

            // P -> bf16 PV A-frags: v_cvt_pk_bf16_f32 + permlane32_swap
            s16x8 pa[2];
#pragma unroll
            for (int s = 0; s < 2; ++s){
                unsigned a1 = cvtpk(p[8*s+0], p[8*s+1]);
                unsigned b1 = cvtpk(p[8*s+4], p[8*s+5]);
                unsigned a2 = cvtpk(p[8*s+2], p[8*s+3]);
                unsigned b2 = cvtpk(p[8*s+6], p[8*s+7]);
                asm("v_permlane32_swap_b32 %0, %1" : "+v"(a1), "+v"(b1));
                asm("v_permlane32_swap_b32 %0, %1" : "+v"(a2), "+v"(b2));
                union { unsigned w[4]; s16x8 v; } u;
                u.w[0] = a1; u.w[1] = a2; u.w[2] = b1; u.w[3] = b2;
                pa[s] = u.v;
            }

            // O += P V : compiler inserts the waitcnt for vf before first use
            __builtin_amdgcn_s_setprio(1);
            oa0 = __builtin_amdgcn_mfma_f32_32x32x16_bf16(pa[0], vf00, oa0, 0, 0, 0);
            oa1 = __builtin_amdgcn_mfma_f32_32x32x16_bf16(pa[0], vf01, oa1, 0, 0, 0);
            oa0 = __builtin_amdgcn_mfma_f32_32x32x16_bf16(pa[1], vf10, oa0, 0, 0, 0);
            oa1 = __builtin_amdgcn_mfma_f32_32x32x16_bf16(pa[1], vf11, oa1, 0, 0, 0);
            __builtin_amdgcn_s_setprio(0);

            kb_cur = kbn;
            buf ^= 1;
        }
    }
#undef STAGE

    // ---- epilogue (dense stores; msm spans both dead K buffers = 16 KB) ----
    float lpf = lp + __shfl_xor(lp, 32);      // l over this wave's 32 k-cols

    __syncthreads();                           // drains stages; KV dead
    float* msm = (float*)&KV[0][0];            // 4096 f32 (16 KB)

    if (kh == 1){
#pragma unroll
        for (int r = 0; r < 16; ++r){
            const int o = (qh*32 + ((r&3) + 8*(r>>2) + 4*hi)) * 64;
            msm[o +      l31] = oa0[r];
            msm[o + 32 + l31] = oa1[r];
        }
        if (lane < 32) lsm[qh*32 + lane] = lpf;
    }
    __syncthreads();

    if (kh == 0){
#pragma unroll
        for (int r = 0; r < 16; ++r){
            const int o = (qh*32 + ((r&3) + 8*(r>>2) + 4*hi)) * 64;
            msm[o +      l31] += oa0[r];
            msm[o + 32 + l31] += oa1[r];
        }
        if (lane < 32){
            float lt = lpf + lsm[qh*32 + lane];
            lsm[qh*32 + lane] = (wq < 0) ? (lt > 0.f ? 1.0f / lt : 0.f) : lt;
        }
    }
    __syncthreads();

    const size_t obase = hoff + (size_t)(qb*64) * DH;   // 16KB output block

    if (wq < 0){
#pragma unroll
        for (int i = 0; i < 4; ++i){
            const int idx = i*1024 + tid*4;
            f32x4 vv = *(const f32x4*)&msm[idx];
            vv *= lsm[idx >> 6];
            *(f32x4*)&out[obase + idx] = vv;
        }
    } else {
        float* pp = part + ((size_t)(h*2 + wq)*8 + sp) * SLOT_F;
#pragma unroll
        for (int i = 0; i < 4; ++i){
            const int idx = i*1024 + tid*4;
            *(f32x4*)&pp[idx] = *(const f32x4*)&msm[idx];
        }
        if (tid < 64) pp[4096 + tid] = lsm[tid];
    }
}

// ============ kernel 3: combine split partials for qb in {0,63} ============
__global__ __launch_bounds__(256) void bb_comb(
        const float* __restrict__ part, float* __restrict__ out)
{
    const int h = blockIdx.x >> 1, wq = blockIdx.x & 1;
    const int qb = wq ? 63 : 0;
    const int tid = threadIdx.x;
    const int i = tid >> 2, cg = (tid & 3) * 16;

    const float* base = part + (size_t)(h*2 + wq) * 8 * SLOT_F;
    f32x4 acc[4] = {{0,0,0,0},{0,0,0,0},{0,0,0,0},{0,0,0,0}};
    float ls = 0.f;
#pragma unroll
    for (int s = 0; s < 8; ++s){
        const float* p = base + (size_t)s * SLOT_F;
#pragma unroll
        for (int c4 = 0; c4 < 4; ++c4)
            acc[c4] += *(const f32x4*)(p + (size_t)i*DH + cg + c4*4);
        ls += p[4096 + i];
    }
    const float inv = ls > 0.f ? 1.0f / ls : 0.f;
    float* op = out + (size_t)h*SEQ*DH + (size_t)(qb*64 + i)*DH + cg;
#pragma unroll
    for (int c4 = 0; c4 < 4; ++c4){
        f32x4 r = acc[c4] * inv;
        *(f32x4*)(op + c4*4) = r;
    }
}

// ============ fallback (used if ws too small) ============
__global__ __launch_bounds__(256) void bb_attn_fb(
        const float* __restrict__ q, const float* __restrict__ k,
        const float* __restrict__ v, const int* __restrict__ mask,
        float* __restrict__ out)
{
    const int qb   = blockIdx.x;
    const int h    = blockIdx.y;
    const int tid  = threadIdx.x;
    const int wave = tid >> 6;
    const int lane = tid & 63;
    const int lrow = lane & 15;
    const int lgrp = lane >> 4;

    __shared__ __align__(16) ushort_t Kb[64*64];
    __shared__ __align__(16) ushort_t Vt[64*64];
    __shared__ __align__(16) ushort_t Pw[4][16*64];

    const size_t hoff = (size_t)h * SEQ * DH;
    const int qrow = qb*64 + wave*16 + lrow;
    const float* qp = q + hoff + (size_t)qrow * DH + lgrp*8;
    s16x8 qf[2];
#pragma unroll
    for (int kc = 0; kc < 2; ++kc){
        f32x4 a = *(const f32x4*)(qp + kc*32);
        f32x4 b = *(const f32x4*)(qp + kc*32 + 4);
        a *= 0.125f; b *= 0.125f;
        qf[kc] = pack8(a, b);
    }
    const f32x4 zero = {0.f,0.f,0.f,0.f};
    f32x4 oa[4] = {zero, zero, zero, zero};
    float m_run[4] = {-1e30f,-1e30f,-1e30f,-1e30f};
    float l_run[4] = {0.f,0.f,0.f,0.f};
    const int* mrow = mask + (size_t)(qb*64) * SEQ;
    const int kr  = tid >> 2, kcg  = tid & 3;
    const int j2  = tid >> 3, dgrp = tid & 7;

    for (int kb = 0; kb < NB; ++kb){
        if (mrow[kb*64] == 0) continue;
        __syncthreads();
        {
            const float* kp = k + hoff + (size_t)(kb*64 + kr) * DH + kcg*16;
            f32x4 a0 = *(const f32x4*)(kp);
            f32x4 a1 = *(const f32x4*)(kp+4);
            f32x4 a2 = *(const f32x4*)(kp+8);
            f32x4 a3 = *(const f32x4*)(kp+12);
            *(s16x8*)&Kb[(kr*64) + (kcg*16     ^ ((kr&7)<<3))] = pack8(a0, a1);
            *(s16x8*)&Kb[(kr*64) + ((kcg*16+8) ^ ((kr&7)<<3))] = pack8(a2, a3);
        }
        {
            const float* vp0 = v + hoff + (size_t)(kb*64 + 2*j2) * DH + dgrp*8;
            f32x4 b0 = *(const f32x4*)(vp0);
            f32x4 b1 = *(const f32x4*)(vp0+4);
            f32x4 b2 = *(const f32x4*)(vp0+DH);
            f32x4 b3 = *(const f32x4*)(vp0+DH+4);
            float r0[8] = {b0[0],b0[1],b0[2],b0[3],b1[0],b1[1],b1[2],b1[3]};
            float r1[8] = {b2[0],b2[1],b2[2],b2[3],b3[0],b3[1],b3[2],b3[3]};
#pragma unroll
            for (int i = 0; i < 8; ++i){
                int dd = (i + dgrp) & 7;
                int d  = dgrp*8 + dd;
                unsigned val = (unsigned)f2bf(r0[dd]) | ((unsigned)f2bf(r1[dd]) << 16);
                *(unsigned*)&Vt[(d*64) + (2*j2 ^ ((d&7)<<3))] = val;
            }
        }
        __syncthreads();
        f32x4 sa[4] = {zero, zero, zero, zero};
#pragma unroll
        for (int jt = 0; jt < 4; ++jt)
#pragma unroll
            for (int kc = 0; kc < 2; ++kc){
                int row = jt*16 + lrow, col = kc*32 + lgrp*8;
                s16x8 kf = *(const s16x8*)&Kb[row*64 + (col ^ ((row&7)<<3))];
                sa[jt] = __builtin_amdgcn_mfma_f32_16x16x32_bf16(qf[kc], kf, sa[jt], 0, 0, 0);
            }
        float fac[4];
#pragma unroll
        for (int r = 0; r < 4; ++r){
            float mx = fmaxf(fmaxf(sa[0][r], sa[1][r]), fmaxf(sa[2][r], sa[3][r]));
            mx = fmaxf(mx, __shfl_xor(mx, 1));
            mx = fmaxf(mx, __shfl_xor(mx, 2));
            mx = fmaxf(mx, __shfl_xor(mx, 4));
            mx = fmaxf(mx, __shfl_xor(mx, 8));
            float mn = fmaxf(m_run[r], mx);
            fac[r] = __expf(m_run[r] - mn);
            m_run[r] = mn;
        }
#pragma unroll
        for (int r = 0; r < 4; ++r){
            float p0 = __expf(sa[0][r] - m_run[r]);
            float p1 = __expf(sa[1][r] - m_run[r]);
            float p2 = __expf(sa[2][r] - m_run[r]);
            float p3 = __expf(sa[3][r] - m_run[r]);
            sa[0][r]=p0; sa[1][r]=p1; sa[2][r]=p2; sa[3][r]=p3;
            float sm = p0+p1+p2+p3;
            sm += __shfl_xor(sm, 1);
            sm += __shfl_xor(sm, 2);
            sm += __shfl_xor(sm, 4);
            sm += __shfl_xor(sm, 8);
            l_run[r] = l_run[r]*fac[r] + sm;
        }
#pragma unroll
        for (int dc = 0; dc < 4; ++dc)
#pragma unroll
            for (int r = 0; r < 4; ++r) oa[dc][r] *= fac[r];
#pragma unroll
        for (int jt = 0; jt < 4; ++jt)
#pragma unroll
            for (int r = 0; r < 4; ++r){
                int row = lgrp*4 + r, col = jt*16 + lrow;
                Pw[wave][row*64 + (col ^ ((row&7)<<3))] = f2bf(sa[jt][r]);
            }
        s16x8 pf0 = *(const s16x8*)&Pw[wave][lrow*64 + ((     lgrp*8) ^ ((lrow&7)<<3))];
        s16x8 pf1 = *(const s16x8*)&Pw[wave][lrow*64 + ((32 + lgrp*8) ^ ((lrow&7)<<3))];
#pragma unroll
        for (int dc = 0; dc < 4; ++dc){
            int row0 = dc*16 + lrow;
            s16x8 v0 = *(const s16x8*)&Vt[row0*64 + ((     lgrp*8) ^ ((row0&7)<<3))];
            s16x8 v1 = *(const s16x8*)&Vt[row0*64 + ((32 + lgrp*8) ^ ((row0&7)<<3))];
            oa[dc] = __builtin_amdgcn_mfma_f32_16x16x32_bf16(pf0, v0, oa[dc], 0, 0, 0);
            oa[dc] = __builtin_amdgcn_mfma_f32_16x16x32_bf16(pf1, v1, oa[dc], 0, 0, 0);
        }
    }
    float inv[4];
#pragma unroll
    for (int r = 0; r < 4; ++r) inv[r] = 1.0f / l_run[r];
    float* op = out + hoff + (size_t)(qb*64 + wave*16) * DH;
#pragma unroll
    for (int dc = 0; dc < 4; ++dc)
#pragma unroll
        for (int r = 0; r < 4; ++r)
            op[(size_t)(lgrp*4 + r) * DH + dc*16 + lrow] = oa[dc][r] * inv[r];
}

extern "C" void kernel_launch(void* const* d_in, const int* in_sizes, int n_in,
                              void* d_out, int out_size, void* d_ws, size_t ws_size,
                              hipStream_t stream)
{
    const float* q    = (const float*)d_in[0];
    const float* k    = (const float*)d_in[1];
    const float* v    = (const float*)d_in[2];
    const int*   mask = (const int*)d_in[3];
    float* out = (float*)d_out;

    if (ws_size < (size_t)WS_NEED){
        dim3 grid(NB, NH, 1);
        bb_attn_fb<<<grid, 256, 0, stream>>>(q, k, v, mask, out);
        return;
    }

    char* ws = (char*)d_ws;
    ushort_t* kbf = (ushort_t*)(ws + KBF_OFF);
    ushort_t* vtb = (ushort_t*)(ws + VTB_OFF);
    float*    prt = (float*)   (ws + PART_OFF);
    u64*      bmp = (u64*)     (ws + BMP_OFF);

    bb_conv<<<dim3(768, 1, 1), 256, 0, stream>>>(k, v, mask, kbf, vtb, bmp);
    bb_main<<<dim3(936, 1, 1), 256, 0, stream>>>(q, kbf, vtb, bmp, out, prt);
    bb_comb<<<dim3(24, 1, 1), 256, 0, stream>>>(prt, out);
}